// Round 8
// baseline (160.243 us; speedup 1.0000x reference)
//
#include <hip/hip_runtime.h>
#include <math.h>

#define D_MODEL 1024
#define T_SEQ   2048
#define NBATCH  4
#define NROWS   (NBATCH * T_SEQ)          // 8192
#define NOUT    64                        // 32 q + 32 k

// tab int offsets
#define T16F   1024   // flag16: 0 = expected m89 layout, else fallback

typedef float  v4f  __attribute__((ext_vector_type(4)));
typedef _Float16 v8hf __attribute__((ext_vector_type(8)));

// ---------- top-4 helpers: total order = (value desc, index asc) ----------
__device__ __forceinline__ bool key_gt(float av, int ai, float bv, int bi) {
    return (av > bv) || (av == bv && ai < bi);
}

__device__ __forceinline__ void cmpswap(float& v0, int& i0, float& v1, int& i1) {
    bool sw = key_gt(v1, i1, v0, i0);
    float nv0 = sw ? v1 : v0, nv1 = sw ? v0 : v1;
    int   ni0 = sw ? i1 : i0, ni1 = sw ? i0 : i1;
    v0 = nv0; v1 = nv1; i0 = ni0; i1 = ni1;
}

// merge sorted-desc a[4] with sorted-desc b[4] -> top4 of union into a (bitonic)
__device__ __forceinline__ void merge4(float (&a)[4], int (&ai)[4],
                                       float b0, int j0, float b1, int j1,
                                       float b2, int j2, float b3, int j3) {
    if (!key_gt(a[0], ai[0], b3, j3)) { a[0] = b3; ai[0] = j3; }
    if (!key_gt(a[1], ai[1], b2, j2)) { a[1] = b2; ai[1] = j2; }
    if (!key_gt(a[2], ai[2], b1, j1)) { a[2] = b1; ai[2] = j1; }
    if (!key_gt(a[3], ai[3], b0, j0)) { a[3] = b0; ai[3] = j0; }
    cmpswap(a[0], ai[0], a[2], ai[2]);
    cmpswap(a[1], ai[1], a[3], ai[3]);
    cmpswap(a[0], ai[0], a[1], ai[1]);
    cmpswap(a[2], ai[2], a[3], ai[3]);
}

__device__ __forceinline__ void insert4(float (&tv)[4], int (&tix)[4], float v, int idx) {
    if (v > tv[3]) {
        bool g0 = v > tv[0], g1 = v > tv[1], g2 = v > tv[2];
        float n0 = g0 ? v : tv[0];
        int   m0 = g0 ? idx : tix[0];
        float n1 = g1 ? (g0 ? tv[0] : v) : tv[1];
        int   m1 = g1 ? (g0 ? tix[0] : idx) : tix[1];
        float n2 = g2 ? (g1 ? tv[1] : v) : tv[2];
        int   m2 = g2 ? (g1 ? tix[1] : idx) : tix[2];
        float n3 = g2 ? tv[2] : v;
        int   m3 = g2 ? tix[2] : idx;
        tv[0] = n0; tv[1] = n1; tv[2] = n2; tv[3] = n3;
        tix[0] = m0; tix[1] = m1; tix[2] = m2; tix[3] = m3;
    }
}

// ---------- f16 MFMA (16x16x32) layout probe ----------
// Verifies A/B mapping (A: row=lane&15, k=(lane>>4)*8+j; B mirrored) and the
// m89 D layout (c[i] at row 4*(lane>>4)+i, col lane&15). Exact-integer
// asymmetric inputs. flag16 != 0 -> scalar f64 fallback everywhere.
__device__ void run_probe16(int tid, int* __restrict__ tab)
{
    __shared__ _Float16 A16[16][32];
    __shared__ _Float16 B16[32][16];
    __shared__ float    D16[16][16];

    for (int e = tid; e < 512; e += 256) {
        const int m = e >> 5, k = e & 31;
        A16[m][k] = (_Float16)(float)(1 + (3 * m + 5 * k) % 61);
        const int kk = e >> 4, n = e & 15;
        B16[kk][n] = (_Float16)(float)(1 + (7 * kk + 11 * n) % 59);
    }
    __syncthreads();
    {
        const int m = tid >> 4, n = tid & 15;
        float s = 0.f;
        for (int k = 0; k < 32; ++k) s += (float)A16[m][k] * (float)B16[k][n];
        D16[m][n] = s;
    }
    __syncthreads();

    if (tid >= 64) return;
    const int lane = tid;

    v8hf a, b;
    const int ab = (lane >> 4) * 8;
    #pragma unroll
    for (int j = 0; j < 8; ++j) {
        a[j] = A16[lane & 15][ab + j];
        b[j] = B16[ab + j][lane & 15];
    }
    v4f c = {0.f, 0.f, 0.f, 0.f};
    c = __builtin_amdgcn_mfma_f32_16x16x32_f16(a, b, c, 0, 0, 0);

    bool ok0 = true;
    #pragma unroll
    for (int i = 0; i < 4; ++i)
        ok0 = ok0 && (c[i] == D16[4 * (lane >> 4) + i][lane & 15]);
    if (lane == 0) tab[T16F] = __all(ok0) ? 0 : -1;
}

// ---------- Phase 1: W prep (blocks 0..255) + x f16-split (all) + probe ----------
// grid 1024 x 256. x split: 2,097,152 float4s, 8 per thread, fully coalesced
// (~100 MB streamed ~12us). Removes ALL f32->f16 conversion VALU from proj.
__global__ __launch_bounds__(256) void wprep_probe(
    const float* __restrict__ x,
    const float* __restrict__ Wq, const float* __restrict__ Wk,
    double* __restrict__ Wdt, _Float16* __restrict__ Wh, _Float16* __restrict__ Wl,
    _Float16* __restrict__ Xh, _Float16* __restrict__ Xl, int do_xsplit,
    int* __restrict__ tab)
{
    const int tid = threadIdx.x;
    const int gid = blockIdx.x * 256 + tid;

    if (gid < 65536) {
        {   // f64 transposed layout Wdt[d][64] (scalar fallback)
            const int o = gid & 63;
            const int d = gid >> 6;
            float v = (o < 32) ? Wq[(size_t)o * D_MODEL + d]
                               : Wk[(size_t)(o - 32) * D_MODEL + d];
            Wdt[(size_t)d * 64 + o] = (double)v;
        }
        {   // f16 split, row layout Wh/Wl[out][d]
            const int o = gid >> 10;
            const int d = gid & 1023;
            float v = (o < 32) ? Wq[(size_t)o * D_MODEL + d]
                               : Wk[(size_t)(o - 32) * D_MODEL + d];
            _Float16 h = (_Float16)v;
            Wh[(size_t)o * D_MODEL + d] = h;
            Wl[(size_t)o * D_MODEL + d] = (_Float16)(v - (float)h);
        }
    }

    if (do_xsplit) {
        #pragma unroll
        for (int j = 0; j < 8; ++j) {
            const size_t f4 = (size_t)j * 262144 + gid;
            float4 v = reinterpret_cast<const float4*>(x)[f4];
            const float f[4] = {v.x, v.y, v.z, v.w};
            union { _Float16 h[4]; short4 s; } uh, ul;
            #pragma unroll
            for (int e = 0; e < 4; ++e) {
                _Float16 h = (_Float16)f[e];
                uh.h[e] = h;
                ul.h[e] = (_Float16)(f[e] - (float)h);
            }
            reinterpret_cast<short4*>(Xh)[f4] = uh.s;
            reinterpret_cast<short4*>(Xl)[f4] = ul.s;
        }
    }

    if (blockIdx.x == 0) run_probe16(tid, tab);
}

// ---------- Phase 2: projection, LDS-free, barrier-free ----------
// grid 512 (16 rows/block), block 256 (4 waves, wave = out-group og).
// Full-K chains: 32 kc x {4 f16 loads + 3 MFMA}. launch_bounds(256,4) pins
// VGPR cap at 128 (~45 live -> NO SPILL; rounds 3-7 lesson: the allocator
// spills silently when occupancy-targeted — cap it explicitly).
__global__ __launch_bounds__(256, 4) void proj(
    const float* __restrict__ x, const double* __restrict__ Wdt,
    const _Float16* __restrict__ Wh, const _Float16* __restrict__ Wl,
    const _Float16* __restrict__ Xh, const _Float16* __restrict__ Xl, int use_xsplit,
    const float* __restrict__ bq, const float* __restrict__ bk_,
    const int* __restrict__ tab,
    float* __restrict__ Qt, float* __restrict__ Kt,
    _Float16* __restrict__ Qh, _Float16* __restrict__ Ql,
    _Float16* __restrict__ Kh, _Float16* __restrict__ Kl)
{
    const int tid  = threadIdx.x;
    const int lane = tid & 63;
    const int wav  = tid >> 6;                                    // 0..3
    const int og   = __builtin_amdgcn_readfirstlane(wav);
    const int row0 = blockIdx.x * 16;

    if (tab[T16F] == 0) {
        const int m  = lane & 15;
        const int ko = (lane >> 4) * 8;
        const _Float16* bH = Wh + (size_t)(og * 16 + m) * D_MODEL + ko;
        const _Float16* bL = Wl + (size_t)(og * 16 + m) * D_MODEL + ko;

        v4f hh = {0.f, 0.f, 0.f, 0.f};
        v4f hl = {0.f, 0.f, 0.f, 0.f};
        v4f lh = {0.f, 0.f, 0.f, 0.f};

        if (use_xsplit) {
            const _Float16* aH = Xh + (size_t)(row0 + m) * D_MODEL + ko;
            const _Float16* aL = Xl + (size_t)(row0 + m) * D_MODEL + ko;
            #pragma unroll 4
            for (int kc = 0; kc < 32; ++kc) {
                v8hf ah = *reinterpret_cast<const v8hf*>(aH + kc * 32);
                v8hf al = *reinterpret_cast<const v8hf*>(aL + kc * 32);
                v8hf bh = *reinterpret_cast<const v8hf*>(bH + kc * 32);
                v8hf bl = *reinterpret_cast<const v8hf*>(bL + kc * 32);
                hh = __builtin_amdgcn_mfma_f32_16x16x32_f16(ah, bh, hh, 0, 0, 0);
                hl = __builtin_amdgcn_mfma_f32_16x16x32_f16(ah, bl, hl, 0, 0, 0);
                lh = __builtin_amdgcn_mfma_f32_16x16x32_f16(al, bh, lh, 0, 0, 0);
            }
        } else {
            const float* xrow = x + (size_t)(row0 + m) * D_MODEL + ko;
            #pragma unroll 4
            for (int kc = 0; kc < 32; ++kc) {
                float4 x0 = *reinterpret_cast<const float4*>(xrow + kc * 32);
                float4 x1 = *reinterpret_cast<const float4*>(xrow + kc * 32 + 4);
                const float f[8] = {x0.x, x0.y, x0.z, x0.w, x1.x, x1.y, x1.z, x1.w};
                v8hf ah, al;
                #pragma unroll
                for (int e = 0; e < 8; ++e) {
                    _Float16 h = (_Float16)f[e];
                    ah[e] = h;
                    al[e] = (_Float16)(f[e] - (float)h);
                }
                v8hf bh = *reinterpret_cast<const v8hf*>(bH + kc * 32);
                v8hf bl = *reinterpret_cast<const v8hf*>(bL + kc * 32);
                hh = __builtin_amdgcn_mfma_f32_16x16x32_f16(ah, bh, hh, 0, 0, 0);
                hl = __builtin_amdgcn_mfma_f32_16x16x32_f16(ah, bl, hl, 0, 0, 0);
                lh = __builtin_amdgcn_mfma_f32_16x16x32_f16(al, bh, lh, 0, 0, 0);
            }
        }

        #pragma unroll
        for (int i = 0; i < 4; ++i) {
            const float t = (hh[i] + hl[i]) + lh[i];   // fixed combine order
            const int o   = og * 16 + m;               // m89 D layout: col = lane&15
            const int row = row0 + 4 * (lane >> 4) + i;
            const float bias = (o < 32) ? bq[o] : bk_[o - 32];
            const float v = t + bias;
            const _Float16 h = (_Float16)v;
            const _Float16 l = (_Float16)(v - (float)h);
            if (o < 32) {
                Qh[(size_t)row * 32 + o] = h;
                Ql[(size_t)row * 32 + o] = l;
            } else {
                Kh[(size_t)row * 32 + (o - 32)] = h;
                Kl[(size_t)row * 32 + (o - 32)] = l;
            }
        }
        return;
    }

    // ---------------- scalar f64 fallback (probe16 failed) ----------------
    {
        const int n  = lane & 15;
        const int r4 = (lane >> 4) * 4;
        const int o  = og * 16 + n;
        const double* wcol = Wdt + o;
        double acc[4] = {0.0, 0.0, 0.0, 0.0};
        for (int d = 0; d < D_MODEL; ++d) {
            double wv = wcol[(size_t)d * 64];
            #pragma unroll
            for (int i = 0; i < 4; ++i)
                acc[i] = fma((double)x[(size_t)(row0 + r4 + i) * D_MODEL + d], wv, acc[i]);
        }
        #pragma unroll
        for (int i = 0; i < 4; ++i) {
            const int row = row0 + r4 + i;
            const int bb  = row >> 11, tt = row & 2047;
            const double bias = (o < 32) ? (double)bq[o] : (double)bk_[o - 32];
            const float v = (float)(acc[i] + bias);
            if (o < 32) Qt[((size_t)bb * 32 + o) * T_SEQ + tt] = v;
            else        Kt[((size_t)bb * 32 + (o - 32)) * T_SEQ + tt] = v;
        }
    }
}

// ---------- Phase 3: MFMA sim (operand-swapped) + top-4 + gather ----------
// grid 512 = b(4) x ttile(128 x 16 rows); block 512 (8 waves; wave owns
// s-range wav*256, 16 st iters). OPERAND SWAP: c = mfma(K_tile, Q_tile) so
// D rows = s, cols = t -> each lane tracks top-4 for ONE t-row: tv[4]/tix[4]
// (8 regs, was 32). Term order (Kh*Qh),(Kl*Qh),(Kh*Ql),(Kl*Ql) reproduces the
// old (Qh*Kh),(Qh*Kl),(Ql*Kh),(Ql*Kl) partial-sum sequence exactly (f16 mul
// commutes bitwise; in-instruction k-order fixed) -> bit-identical sims.
// Butterfly shrinks to masks {16,32}. launch_bounds(512,4): VGPR cap 128,
// ~40 live -> no spill (rounds 3-7 lesson).
__global__ __launch_bounds__(512, 4) void sim_topk_gather(
    const float* __restrict__ x,
    const _Float16* __restrict__ Qh, const _Float16* __restrict__ Ql,
    const _Float16* __restrict__ Kh, const _Float16* __restrict__ Kl,
    const float* __restrict__ Qt, const float* __restrict__ Kt,
    const int* __restrict__ tab,
    float* __restrict__ out)
{
    __shared__ float sV[8][16][4];
    __shared__ int   sI[8][16][4];
    __shared__ float sVf[16][32][4];
    __shared__ int   sIf[16][32][4];
    __shared__ int   topIdx[16][4];

    const int tid  = threadIdx.x;
    const int lane = tid & 63;
    const int wav  = tid >> 6;            // 0..7
    const int tt   = blockIdx.x & 127;
    const int b    = blockIdx.x >> 7;
    const int row0g = b * T_SEQ + tt * 16;   // global row base

    if (tab[T16F] == 0) {
        const int m  = lane & 15;
        const int ko = (lane >> 4) * 8;
        // Q as B-operand: col t = lane&15 -> row (row0g + m). Same address as before.
        v8hf qh = *reinterpret_cast<const v8hf*>(Qh + (size_t)(row0g + m) * 32 + ko);
        v8hf ql = *reinterpret_cast<const v8hf*>(Ql + (size_t)(row0g + m) * 32 + ko);
        const _Float16* KhB = Kh + (size_t)b * T_SEQ * 32;
        const _Float16* KlB = Kl + (size_t)b * T_SEQ * 32;

        float tv[4]; int tix[4];
        #pragma unroll
        for (int j = 0; j < 4; ++j) { tv[j] = -INFINITY; tix[j] = 0x7fffffff; }

        const int sq = wav * 256;
        #pragma unroll 4
        for (int st = 0; st < 16; ++st) {
            const int s0 = sq + st * 16;
            v8hf kh = *reinterpret_cast<const v8hf*>(KhB + (size_t)(s0 + m) * 32 + ko);
            v8hf kl = *reinterpret_cast<const v8hf*>(KlB + (size_t)(s0 + m) * 32 + ko);
            v4f c = {0.f, 0.f, 0.f, 0.f};
            c = __builtin_amdgcn_mfma_f32_16x16x32_f16(kh, qh, c, 0, 0, 0);
            c = __builtin_amdgcn_mfma_f32_16x16x32_f16(kl, qh, c, 0, 0, 0);
            c = __builtin_amdgcn_mfma_f32_16x16x32_f16(kh, ql, c, 0, 0, 0);
            c = __builtin_amdgcn_mfma_f32_16x16x32_f16(kl, ql, c, 0, 0, 0);
            // D row = s offset: c[i] is sim(t = lane&15, s = s0 + 4*(lane>>4)+i)
            const int sb = s0 + 4 * (lane >> 4);
            #pragma unroll
            for (int i = 0; i < 4; ++i) insert4(tv, tix, c[i], sb + i);
        }

        // butterfly masks 16,32: merge the 4 lane-groups sharing t = lane&15
        #pragma unroll
        for (int mk = 16; mk <= 32; mk <<= 1) {
            float b0 = __shfl_xor(tv[0], mk, 64);
            float b1 = __shfl_xor(tv[1], mk, 64);
            float b2 = __shfl_xor(tv[2], mk, 64);
            float b3 = __shfl_xor(tv[3], mk, 64);
            int   j0 = __shfl_xor(tix[0], mk, 64);
            int   j1 = __shfl_xor(tix[1], mk, 64);
            int   j2 = __shfl_xor(tix[2], mk, 64);
            int   j3 = __shfl_xor(tix[3], mk, 64);
            merge4(tv, tix, b0, j0, b1, j1, b2, j2, b3, j3);
        }

        if (lane < 16) {
            #pragma unroll
            for (int j = 0; j < 4; ++j) {
                sV[wav][lane][j] = tv[j];
                sI[wav][lane][j] = tix[j];
            }
        }
        __syncthreads();

        if (tid < 16) {
            float mv[4]; int mi[4];
            #pragma unroll
            for (int j = 0; j < 4; ++j) { mv[j] = sV[0][tid][j]; mi[j] = sI[0][tid][j]; }
            #pragma unroll
            for (int w = 1; w < 8; ++w)
                merge4(mv, mi,
                       sV[w][tid][0], sI[w][tid][0],
                       sV[w][tid][1], sI[w][tid][1],
                       sV[w][tid][2], sI[w][tid][2],
                       sV[w][tid][3], sI[w][tid][3]);
            #pragma unroll
            for (int j = 0; j < 4; ++j) topIdx[tid][j] = mi[j];
        }
        __syncthreads();
    } else {
        // ---- f32 fallback from Qt/Kt ----
        const float* QtB = Qt + (size_t)b * 32 * T_SEQ;
        const float* KtB = Kt + (size_t)b * 32 * T_SEQ;
        const int row   = tid >> 5;        // 0..15
        const int chunk = tid & 31;        // 32 chunks x 64 s
        const int trow  = tt * 16 + row;
        float q[32];
        #pragma unroll 8
        for (int i = 0; i < 32; ++i) q[i] = QtB[(size_t)i * T_SEQ + trow];
        float tv4[4]; int tix4[4];
        #pragma unroll
        for (int j = 0; j < 4; ++j) { tv4[j] = -INFINITY; tix4[j] = 0x7fffffff; }
        const int sbeg = chunk * 64;
        for (int s = sbeg; s < sbeg + 64; ++s) {
            float sum = 0.f;
            #pragma unroll 8
            for (int i = 0; i < 32; ++i)
                sum = fmaf(q[i], KtB[(size_t)i * T_SEQ + s], sum);
            insert4(tv4, tix4, sum, s);
        }
        #pragma unroll
        for (int j = 0; j < 4; ++j) { sVf[row][chunk][j] = tv4[j]; sIf[row][chunk][j] = tix4[j]; }
        __syncthreads();
        if (tid < 16) {
            float mv[4]; int mi[4];
            #pragma unroll
            for (int j = 0; j < 4; ++j) { mv[j] = sVf[tid][0][j]; mi[j] = sIf[tid][0][j]; }
            for (int cc = 1; cc < 32; ++cc)
                merge4(mv, mi,
                       sVf[tid][cc][0], sIf[tid][cc][0],
                       sVf[tid][cc][1], sIf[tid][cc][1],
                       sVf[tid][cc][2], sIf[tid][cc][2],
                       sVf[tid][cc][3], sIf[tid][cc][3]);
            #pragma unroll
            for (int j = 0; j < 4; ++j) topIdx[tid][j] = mi[j];
        }
        __syncthreads();
    }

    // gather + mean: 512 threads, 2 rows per pass (each row = 256 float4)
    const float* xb = x + (size_t)b * T_SEQ * D_MODEL;
    float* ob = out + (size_t)row0g * D_MODEL;
    const int rh = tid >> 8;     // 0..1
    const int t4 = tid & 255;    // float4 column
    #pragma unroll 2
    for (int rp = 0; rp < 8; ++rp) {
        const int r = rp * 2 + rh;
        const int i0 = topIdx[r][0], i1 = topIdx[r][1], i2 = topIdx[r][2], i3 = topIdx[r][3];
        float4 a0 = *(reinterpret_cast<const float4*>(xb + (size_t)i0 * D_MODEL) + t4);
        float4 a1 = *(reinterpret_cast<const float4*>(xb + (size_t)i1 * D_MODEL) + t4);
        float4 a2 = *(reinterpret_cast<const float4*>(xb + (size_t)i2 * D_MODEL) + t4);
        float4 a3 = *(reinterpret_cast<const float4*>(xb + (size_t)i3 * D_MODEL) + t4);
        float4 o;
        o.x = (a0.x + a1.x + a2.x + a3.x) * 0.25f;
        o.y = (a0.y + a1.y + a2.y + a3.y) * 0.25f;
        o.z = (a0.z + a1.z + a2.z + a3.z) * 0.25f;
        o.w = (a0.w + a1.w + a2.w + a3.w) * 0.25f;
        *(reinterpret_cast<float4*>(ob + (size_t)r * D_MODEL) + t4) = o;
    }
}

extern "C" void kernel_launch(void* const* d_in, const int* in_sizes, int n_in,
                              void* d_out, int out_size, void* d_ws, size_t ws_size,
                              hipStream_t stream) {
    const float* x  = (const float*)d_in[0];
    const float* Wq = (const float*)d_in[1];
    const float* bq = (const float*)d_in[2];
    const float* Wk = (const float*)d_in[3];
    const float* bk = (const float*)d_in[4];
    float* out = (float*)d_out;

    // ws: [tab 8K][Wdt 512K][Wh 128K][Wl 128K][Qt 1M][Kt 1M][Qh..Kl 4x512K][Xh 16.8M][Xl 16.8M]
    char* wsb = (char*)d_ws;
    int*      tab = (int*)wsb;
    double*   Wdt = (double*)(wsb + 8192);
    _Float16* Wh  = (_Float16*)(wsb + 8192 + 524288);
    _Float16* Wl  = (_Float16*)(wsb + 8192 + 524288 + 131072);
    float*    Qt  = (float*)(wsb + 8192 + 524288 + 262144);
    float*    Kt  = Qt + (size_t)NBATCH * 32 * T_SEQ;
    _Float16* Qh  = (_Float16*)((char*)Kt + (size_t)NBATCH * 32 * T_SEQ * 4);
    _Float16* Ql  = Qh + (size_t)NROWS * 32;
    _Float16* Kh  = Ql + (size_t)NROWS * 32;
    _Float16* Kl  = Kh + (size_t)NROWS * 32;
    _Float16* Xh  = Kl + (size_t)NROWS * 32;                      // offset 4,988,928
    _Float16* Xl  = Xh + (size_t)NROWS * D_MODEL;                 // +16.8 MB

    const size_t need = 4988928 + 2 * (size_t)NROWS * D_MODEL * 2;   // ~38.5 MB
    const int use_xsplit = (ws_size >= need) ? 1 : 0;

    wprep_probe<<<dim3(1024), dim3(256), 0, stream>>>(x, Wq, Wk, Wdt, Wh, Wl,
                                                      Xh, Xl, use_xsplit, tab);
    proj<<<dim3(NROWS / 16), dim3(256), 0, stream>>>(x, Wdt, Wh, Wl, Xh, Xl, use_xsplit,
                                                     bq, bk, tab, Qt, Kt, Qh, Ql, Kh, Kl);
    sim_topk_gather<<<dim3(512), dim3(512), 0, stream>>>(x, Qh, Ql, Kh, Kl, Qt, Kt, tab, out);
}

// Round 9
// 145.475 us; speedup vs baseline: 1.1015x; 1.1015x over previous
//
#include <hip/hip_runtime.h>
#include <math.h>

#define D_MODEL 1024
#define T_SEQ   2048
#define NBATCH  4
#define NROWS   (NBATCH * T_SEQ)          // 8192
#define NOUT    64                        // 32 q + 32 k

// tab int offsets
#define T16F   1024   // flag16: 0 = expected m89 layout, else fallback

typedef float  v4f  __attribute__((ext_vector_type(4)));
typedef _Float16 v8hf __attribute__((ext_vector_type(8)));

// ---------- top-4 helpers: total order = (value desc, index asc) ----------
__device__ __forceinline__ bool key_gt(float av, int ai, float bv, int bi) {
    return (av > bv) || (av == bv && ai < bi);
}

__device__ __forceinline__ void cmpswap(float& v0, int& i0, float& v1, int& i1) {
    bool sw = key_gt(v1, i1, v0, i0);
    float nv0 = sw ? v1 : v0, nv1 = sw ? v0 : v1;
    int   ni0 = sw ? i1 : i0, ni1 = sw ? i0 : i1;
    v0 = nv0; v1 = nv1; i0 = ni0; i1 = ni1;
}

// merge sorted-desc a[4] with sorted-desc b[4] -> top4 of union into a (bitonic)
__device__ __forceinline__ void merge4(float (&a)[4], int (&ai)[4],
                                       float b0, int j0, float b1, int j1,
                                       float b2, int j2, float b3, int j3) {
    if (!key_gt(a[0], ai[0], b3, j3)) { a[0] = b3; ai[0] = j3; }
    if (!key_gt(a[1], ai[1], b2, j2)) { a[1] = b2; ai[1] = j2; }
    if (!key_gt(a[2], ai[2], b1, j1)) { a[2] = b1; ai[2] = j1; }
    if (!key_gt(a[3], ai[3], b0, j0)) { a[3] = b0; ai[3] = j0; }
    cmpswap(a[0], ai[0], a[2], ai[2]);
    cmpswap(a[1], ai[1], a[3], ai[3]);
    cmpswap(a[0], ai[0], a[1], ai[1]);
    cmpswap(a[2], ai[2], a[3], ai[3]);
}

__device__ __forceinline__ void insert4(float (&tv)[4], int (&tix)[4], float v, int idx) {
    if (v > tv[3]) {
        bool g0 = v > tv[0], g1 = v > tv[1], g2 = v > tv[2];
        float n0 = g0 ? v : tv[0];
        int   m0 = g0 ? idx : tix[0];
        float n1 = g1 ? (g0 ? tv[0] : v) : tv[1];
        int   m1 = g1 ? (g0 ? tix[0] : idx) : tix[1];
        float n2 = g2 ? (g1 ? tv[1] : v) : tv[2];
        int   m2 = g2 ? (g1 ? tix[1] : idx) : tix[2];
        float n3 = g2 ? tv[2] : v;
        int   m3 = g2 ? tix[2] : idx;
        tv[0] = n0; tv[1] = n1; tv[2] = n2; tv[3] = n3;
        tix[0] = m0; tix[1] = m1; tix[2] = m2; tix[3] = m3;
    }
}

// ---------- f16 MFMA (16x16x32) layout probe, any block size >= 256 ----------
// Verifies A/B mapping (A: row=lane&15, k=(lane>>4)*8+j; B mirrored) and the
// m89 D layout (c[i] at row 4*(lane>>4)+i, col lane&15). Exact-integer
// asymmetric inputs. Runs redundantly in EVERY block (cheap: ~1K cycles);
// returns block-uniform flag via LDS. Block 0 publishes to tab for sim.
__device__ int run_probe16_block(int tid, int nthr, int* __restrict__ tab, int wr)
{
    __shared__ _Float16 A16[16][32];
    __shared__ _Float16 B16[32][16];
    __shared__ float    D16[16][16];
    __shared__ int      flagS;

    for (int e = tid; e < 512; e += nthr) {
        const int m = e >> 5, k = e & 31;
        A16[m][k] = (_Float16)(float)(1 + (3 * m + 5 * k) % 61);
        const int kk = e >> 4, n = e & 15;
        B16[kk][n] = (_Float16)(float)(1 + (7 * kk + 11 * n) % 59);
    }
    __syncthreads();
    for (int e = tid; e < 256; e += nthr) {
        const int m = e >> 4, n = e & 15;
        float s = 0.f;
        for (int k = 0; k < 32; ++k) s += (float)A16[m][k] * (float)B16[k][n];
        D16[m][n] = s;
    }
    __syncthreads();

    if (tid < 64) {
        const int lane = tid;
        v8hf a, b;
        const int ab = (lane >> 4) * 8;
        #pragma unroll
        for (int j = 0; j < 8; ++j) {
            a[j] = A16[lane & 15][ab + j];
            b[j] = B16[ab + j][lane & 15];
        }
        v4f c = {0.f, 0.f, 0.f, 0.f};
        c = __builtin_amdgcn_mfma_f32_16x16x32_f16(a, b, c, 0, 0, 0);
        bool ok0 = true;
        #pragma unroll
        for (int i = 0; i < 4; ++i)
            ok0 = ok0 && (c[i] == D16[4 * (lane >> 4) + i][lane & 15]);
        int found = __all(ok0) ? 0 : -1;
        if (lane == 0) { flagS = found; if (wr) tab[T16F] = found; }
    }
    __syncthreads();
    return flagS;
}

// ---------- Phase 1: fused probe + projection (W/x converted inline) ----------
// grid 512 (16 rows/block), block 1024 = 16 waves: og = wav&3 (out-group),
// kq = wav>>2 (K-quarter, 8 kc iters of 32). Round-8 lessons: (a) x pre-split
// was a net-loss streaming pass — convert inline (W f32 loads are block-shared
// L2 hits); (b) launch_bounds(1024,8) CONTRACTS 8 waves/SIMD -> 64-VGPR cap:
// live ~55, no spill, 32 waves/CU. Quarter partials combined via LDS in fixed
// order (t0+t1)+(t2+t3) -> deterministic (~1e-7 regime, validated r4/r5/r6/r7).
__global__ __launch_bounds__(1024, 8) void proj_fused(
    const float* __restrict__ x,
    const float* __restrict__ Wq, const float* __restrict__ Wk,
    const float* __restrict__ bq, const float* __restrict__ bk_,
    int* __restrict__ tab,
    float* __restrict__ Qt, float* __restrict__ Kt,
    _Float16* __restrict__ Qh, _Float16* __restrict__ Ql,
    _Float16* __restrict__ Kh, _Float16* __restrict__ Kl)
{
    __shared__ float comb[3][4][64][4];   // 12 KB quarter-combine

    const int tid  = threadIdx.x;
    const int lane = tid & 63;
    const int wav  = tid >> 6;                                    // 0..15
    const int og   = __builtin_amdgcn_readfirstlane(wav & 3);
    const int kq   = __builtin_amdgcn_readfirstlane(wav >> 2);
    const int row0 = blockIdx.x * 16;

    const int flag = run_probe16_block(tid, 1024, tab, blockIdx.x == 0);

    if (flag == 0) {
        const int m  = lane & 15;
        const int ko = (lane >> 4) * 8;
        const int kb = kq * 256;
        const int o  = og * 16 + m;
        const float* xrow = x + (size_t)(row0 + m) * D_MODEL + kb + ko;
        const float* wrow = ((o < 32) ? Wq + (size_t)o * D_MODEL
                                      : Wk + (size_t)(o - 32) * D_MODEL) + kb + ko;

        v4f hh = {0.f, 0.f, 0.f, 0.f};
        v4f hl = {0.f, 0.f, 0.f, 0.f};
        v4f lh = {0.f, 0.f, 0.f, 0.f};
        #pragma unroll 2
        for (int kc = 0; kc < 8; ++kc) {
            float4 x0 = *reinterpret_cast<const float4*>(xrow + kc * 32);
            float4 x1 = *reinterpret_cast<const float4*>(xrow + kc * 32 + 4);
            float4 w0 = *reinterpret_cast<const float4*>(wrow + kc * 32);
            float4 w1 = *reinterpret_cast<const float4*>(wrow + kc * 32 + 4);
            const float xf[8] = {x0.x, x0.y, x0.z, x0.w, x1.x, x1.y, x1.z, x1.w};
            const float wf[8] = {w0.x, w0.y, w0.z, w0.w, w1.x, w1.y, w1.z, w1.w};
            v8hf ah, al, bh, bl;
            #pragma unroll
            for (int e = 0; e < 8; ++e) {
                _Float16 h = (_Float16)xf[e];
                ah[e] = h; al[e] = (_Float16)(xf[e] - (float)h);
                _Float16 g = (_Float16)wf[e];
                bh[e] = g; bl[e] = (_Float16)(wf[e] - (float)g);
            }
            hh = __builtin_amdgcn_mfma_f32_16x16x32_f16(ah, bh, hh, 0, 0, 0);
            hl = __builtin_amdgcn_mfma_f32_16x16x32_f16(ah, bl, hl, 0, 0, 0);
            lh = __builtin_amdgcn_mfma_f32_16x16x32_f16(al, bh, lh, 0, 0, 0);
        }

        v4f t;
        #pragma unroll
        for (int i = 0; i < 4; ++i) t[i] = (hh[i] + hl[i]) + lh[i];

        if (kq > 0) {
            #pragma unroll
            for (int i = 0; i < 4; ++i) comb[kq - 1][og][lane][i] = t[i];
        }
        __syncthreads();
        if (kq == 0) {
            #pragma unroll
            for (int i = 0; i < 4; ++i) {
                const float tot = (t[i] + comb[0][og][lane][i])
                                + (comb[1][og][lane][i] + comb[2][og][lane][i]);
                const int row = row0 + 4 * (lane >> 4) + i;   // m89 D layout
                const float bias = (o < 32) ? bq[o] : bk_[o - 32];
                const float v = tot + bias;
                const _Float16 h = (_Float16)v;
                const _Float16 l = (_Float16)(v - (float)h);
                if (o < 32) {
                    Qh[(size_t)row * 32 + o] = h;
                    Ql[(size_t)row * 32 + o] = l;
                } else {
                    Kh[(size_t)row * 32 + (o - 32)] = h;
                    Kl[(size_t)row * 32 + (o - 32)] = l;
                }
            }
        }
        return;
    }

    // ---- scalar f64 fallback (probe failed; register-minimal, kq==0 only) ----
    if (kq == 0) {
        const int n  = lane & 15;
        const int r4 = (lane >> 4) * 4;
        const int o  = og * 16 + n;
        const float* wr = (o < 32) ? Wq + (size_t)o * D_MODEL
                                   : Wk + (size_t)(o - 32) * D_MODEL;
        double acc[4] = {0.0, 0.0, 0.0, 0.0};
        for (int d = 0; d < D_MODEL; ++d) {
            const double wv = (double)wr[d];
            #pragma unroll
            for (int i = 0; i < 4; ++i)
                acc[i] = fma((double)x[(size_t)(row0 + r4 + i) * D_MODEL + d], wv, acc[i]);
        }
        #pragma unroll
        for (int i = 0; i < 4; ++i) {
            const int row = row0 + r4 + i;
            const int bb  = row >> 11, tt = row & 2047;
            const double bias = (o < 32) ? (double)bq[o] : (double)bk_[o - 32];
            const float v = (float)(acc[i] + bias);
            if (o < 32) Qt[((size_t)bb * 32 + o) * T_SEQ + tt] = v;
            else        Kt[((size_t)bb * 32 + (o - 32)) * T_SEQ + tt] = v;
        }
    }
}

// ---------- Phase 2: MFMA sim (operand-swapped) + top-4 + gather ----------
// grid 512 = b(4) x ttile(128 x 16 rows); block 1024 = 16 waves, wave owns
// s-range wav*128 (8 st iters). 8192 waves total = 32/CU (round-8: 16/CU,
// occupancy 32% — wave supply was the binding constraint). launch_bounds
// (1024,8) -> 64-VGPR contract, live ~45. Same bit-exact 4-MFMA term order
// as round 8; top-4-of-union is s-partition-invariant.
__global__ __launch_bounds__(1024, 8) void sim_topk_gather(
    const float* __restrict__ x,
    const _Float16* __restrict__ Qh, const _Float16* __restrict__ Ql,
    const _Float16* __restrict__ Kh, const _Float16* __restrict__ Kl,
    const float* __restrict__ Qt, const float* __restrict__ Kt,
    const int* __restrict__ tab,
    float* __restrict__ out)
{
    __shared__ float sV[16][16][4];
    __shared__ int   sI[16][16][4];
    __shared__ float sVf[16][64][4];
    __shared__ int   sIf[16][64][4];
    __shared__ int   topIdx[16][4];

    const int tid  = threadIdx.x;
    const int lane = tid & 63;
    const int wav  = tid >> 6;            // 0..15
    const int tt   = blockIdx.x & 127;
    const int b    = blockIdx.x >> 7;
    const int row0g = b * T_SEQ + tt * 16;   // global row base

    if (tab[T16F] == 0) {
        const int m  = lane & 15;
        const int ko = (lane >> 4) * 8;
        v8hf qh = *reinterpret_cast<const v8hf*>(Qh + (size_t)(row0g + m) * 32 + ko);
        v8hf ql = *reinterpret_cast<const v8hf*>(Ql + (size_t)(row0g + m) * 32 + ko);
        const _Float16* KhB = Kh + (size_t)b * T_SEQ * 32;
        const _Float16* KlB = Kl + (size_t)b * T_SEQ * 32;

        float tv[4]; int tix[4];
        #pragma unroll
        for (int j = 0; j < 4; ++j) { tv[j] = -INFINITY; tix[j] = 0x7fffffff; }

        const int sq = wav * 128;
        #pragma unroll 2
        for (int st = 0; st < 8; ++st) {
            const int s0 = sq + st * 16;
            v8hf kh = *reinterpret_cast<const v8hf*>(KhB + (size_t)(s0 + m) * 32 + ko);
            v8hf kl = *reinterpret_cast<const v8hf*>(KlB + (size_t)(s0 + m) * 32 + ko);
            v4f c = {0.f, 0.f, 0.f, 0.f};
            c = __builtin_amdgcn_mfma_f32_16x16x32_f16(kh, qh, c, 0, 0, 0);
            c = __builtin_amdgcn_mfma_f32_16x16x32_f16(kl, qh, c, 0, 0, 0);
            c = __builtin_amdgcn_mfma_f32_16x16x32_f16(kh, ql, c, 0, 0, 0);
            c = __builtin_amdgcn_mfma_f32_16x16x32_f16(kl, ql, c, 0, 0, 0);
            // c[i] = sim(t = lane&15, s = s0 + 4*(lane>>4)+i)
            const int sb = s0 + 4 * (lane >> 4);
            #pragma unroll
            for (int i = 0; i < 4; ++i) insert4(tv, tix, c[i], sb + i);
        }

        // butterfly masks 16,32: merge the 4 lane-groups sharing t = lane&15
        #pragma unroll
        for (int mk = 16; mk <= 32; mk <<= 1) {
            float b0 = __shfl_xor(tv[0], mk, 64);
            float b1 = __shfl_xor(tv[1], mk, 64);
            float b2 = __shfl_xor(tv[2], mk, 64);
            float b3 = __shfl_xor(tv[3], mk, 64);
            int   j0 = __shfl_xor(tix[0], mk, 64);
            int   j1 = __shfl_xor(tix[1], mk, 64);
            int   j2 = __shfl_xor(tix[2], mk, 64);
            int   j3 = __shfl_xor(tix[3], mk, 64);
            merge4(tv, tix, b0, j0, b1, j1, b2, j2, b3, j3);
        }

        if (lane < 16) {
            #pragma unroll
            for (int j = 0; j < 4; ++j) {
                sV[wav][lane][j] = tv[j];
                sI[wav][lane][j] = tix[j];
            }
        }
        __syncthreads();

        if (tid < 16) {
            float mv[4]; int mi[4];
            #pragma unroll
            for (int j = 0; j < 4; ++j) { mv[j] = sV[0][tid][j]; mi[j] = sI[0][tid][j]; }
            #pragma unroll
            for (int w = 1; w < 16; ++w)
                merge4(mv, mi,
                       sV[w][tid][0], sI[w][tid][0],
                       sV[w][tid][1], sI[w][tid][1],
                       sV[w][tid][2], sI[w][tid][2],
                       sV[w][tid][3], sI[w][tid][3]);
            #pragma unroll
            for (int j = 0; j < 4; ++j) topIdx[tid][j] = mi[j];
        }
        __syncthreads();
    } else {
        // ---- f32 fallback from Qt/Kt (register-minimal; never runs) ----
        const float* QtB = Qt + (size_t)b * 32 * T_SEQ;
        const float* KtB = Kt + (size_t)b * 32 * T_SEQ;
        const int row   = tid >> 6;        // 0..15
        const int chunk = tid & 63;        // 64 chunks x 32 s
        const int trow  = tt * 16 + row;
        float tv4[4]; int tix4[4];
        #pragma unroll
        for (int j = 0; j < 4; ++j) { tv4[j] = -INFINITY; tix4[j] = 0x7fffffff; }
        for (int s = chunk * 32; s < chunk * 32 + 32; ++s) {
            float sum = 0.f;
            for (int i = 0; i < 32; ++i)
                sum = fmaf(QtB[(size_t)i * T_SEQ + trow], KtB[(size_t)i * T_SEQ + s], sum);
            insert4(tv4, tix4, sum, s);
        }
        #pragma unroll
        for (int j = 0; j < 4; ++j) { sVf[row][chunk][j] = tv4[j]; sIf[row][chunk][j] = tix4[j]; }
        __syncthreads();
        if (tid < 16) {
            float mv[4]; int mi[4];
            #pragma unroll
            for (int j = 0; j < 4; ++j) { mv[j] = sVf[tid][0][j]; mi[j] = sIf[tid][0][j]; }
            for (int cc = 1; cc < 64; ++cc)
                merge4(mv, mi,
                       sVf[tid][cc][0], sIf[tid][cc][0],
                       sVf[tid][cc][1], sIf[tid][cc][1],
                       sVf[tid][cc][2], sIf[tid][cc][2],
                       sVf[tid][cc][3], sIf[tid][cc][3]);
            #pragma unroll
            for (int j = 0; j < 4; ++j) topIdx[tid][j] = mi[j];
        }
        __syncthreads();
    }

    // gather + mean: 1024 threads, 4 rows per pass (each row = 256 float4)
    const float* xb = x + (size_t)b * T_SEQ * D_MODEL;
    float* ob = out + (size_t)row0g * D_MODEL;
    const int rh = tid >> 8;     // 0..3
    const int t4 = tid & 255;    // float4 column
    #pragma unroll
    for (int rp = 0; rp < 4; ++rp) {
        const int r = rp * 4 + rh;
        const int i0 = topIdx[r][0], i1 = topIdx[r][1], i2 = topIdx[r][2], i3 = topIdx[r][3];
        float4 a0 = *(reinterpret_cast<const float4*>(xb + (size_t)i0 * D_MODEL) + t4);
        float4 a1 = *(reinterpret_cast<const float4*>(xb + (size_t)i1 * D_MODEL) + t4);
        float4 a2 = *(reinterpret_cast<const float4*>(xb + (size_t)i2 * D_MODEL) + t4);
        float4 a3 = *(reinterpret_cast<const float4*>(xb + (size_t)i3 * D_MODEL) + t4);
        float4 o;
        o.x = (a0.x + a1.x + a2.x + a3.x) * 0.25f;
        o.y = (a0.y + a1.y + a2.y + a3.y) * 0.25f;
        o.z = (a0.z + a1.z + a2.z + a3.z) * 0.25f;
        o.w = (a0.w + a1.w + a2.w + a3.w) * 0.25f;
        *(reinterpret_cast<float4*>(ob + (size_t)r * D_MODEL) + t4) = o;
    }
}

extern "C" void kernel_launch(void* const* d_in, const int* in_sizes, int n_in,
                              void* d_out, int out_size, void* d_ws, size_t ws_size,
                              hipStream_t stream) {
    const float* x  = (const float*)d_in[0];
    const float* Wq = (const float*)d_in[1];
    const float* bq = (const float*)d_in[2];
    const float* Wk = (const float*)d_in[3];
    const float* bk = (const float*)d_in[4];
    float* out = (float*)d_out;

    // ws: [tab 8K][Qt 1M][Kt 1M][Qh 512K][Ql 512K][Kh 512K][Kl 512K] ~ 4.1 MB
    char* wsb = (char*)d_ws;
    int*      tab = (int*)wsb;
    float*    Qt  = (float*)(wsb + 8192);
    float*    Kt  = Qt + (size_t)NBATCH * 32 * T_SEQ;
    _Float16* Qh  = (_Float16*)((char*)Kt + (size_t)NBATCH * 32 * T_SEQ * 4);
    _Float16* Ql  = Qh + (size_t)NROWS * 32;
    _Float16* Kh  = Ql + (size_t)NROWS * 32;
    _Float16* Kl  = Kh + (size_t)NROWS * 32;

    proj_fused<<<dim3(NROWS / 16), dim3(1024), 0, stream>>>(
        x, Wq, Wk, bq, bk, tab, Qt, Kt, Qh, Ql, Kh, Kl);
    sim_topk_gather<<<dim3(512), dim3(1024), 0, stream>>>(
        x, Qh, Ql, Kh, Kl, Qt, Kt, tab, out);
}